// Round 4
// baseline (148.817 us; speedup 1.0000x reference)
//
#include <hip/hip_runtime.h>

#define S_DIM 363      // GRID = ceil(sqrt(2)*256)
#define S_P   368      // per-angle row stride in 8-B entries (16-B multiple)
#define A_DIM 180      // N_THETA
#define OUT_W 256
#define GRIDN 512      // fused-kernel grid: 2 blocks/CU x 256 CU = co-resident
#define F_PI 3.14159265358979323846f

typedef float    f4 __attribute__((ext_vector_type(4)));
typedef _Float16 h4 __attribute__((ext_vector_type(4)));
union HU { uint2 u; h4 h; };

// Filtered sinogram, plain fp16 layout: g_sino[a*S_P + 1 + t] = y_a[t] for all
// 4 batches (8 B, batch-interleaved). Guards g[a][0] = g[a][364] = 0 reproduce
// the reference's clip+zero-weight edge semantics exactly (k1 = floor(pos)+1
// in [0,363]; lo = entry k1 = y[k1-1] or guard, hi = entry k1+1 = y[k1] or
// guard). Fully rewritten every launch before phase 2 reads it.
__device__ uint2 g_sino[A_DIM * S_P];

// Grid barrier state. Monotonic: every launch adds exactly GRIDN, so the
// counter is a multiple of GRIDN at each launch start -- safe across hip-graph
// replays with no host-side reset (wraps after 2^32/512 = 8.4M launches).
__device__ unsigned g_bar = 0u;

// ---------------------------------------------------------------------------
// Fused kernel, ONE plain dispatch (graph-capturable; R2's
// hipLaunchCooperativeKernel aborted graph capture -> container failure).
// Grid-wide phase boundary = capacity barrier: 512 blocks are co-resident by
// __launch_bounds__(256,2) construction, arrival/wait uses the same
// agent-scope atomic + fence protocol cg::grid::sync() lowers to.
//
// Phase 1 (blocks 0..179, one angle each): ramp filter as direct spatial conv
//   (exact rewrite of the reference FFT path: circular conv, g[0]=0.5,
//   g[d]=-2/(pi*d)^2 odd d, 0 even d; |t-s| <= 362 < 512 so the weight
//   depends only on |t-s|). Threads 0..191 compute outputs t and t+192 (same
//   parity -> shared xs4[s] b128 broadcast read); parity pruning halves the
//   taps; all 4 batches per thread via f4 LDS reads (2 addrs/wave,
//   conflict-free).
//
// Phase 2 (all 512 blocks, 2 output rows each: i = b>>2 and i+128, j-chunk
//   b&3): pos = (j-128)*cos - (i-128)*sin + 181; k1 = floor(pos)+1 in
//   [0,363]; two adjacent 8-B loads (second folds to offset:8) give both
//   interp taps x4 batches; f32 accum via v_fma_mix. 4 waves = 4 angle
//   quarters, partials merged through LDS.
// ---------------------------------------------------------------------------
__global__ __launch_bounds__(256, 2) void iradon_fused_kernel(
        const float* __restrict__ x, float* __restrict__ out) {
    __shared__ f4     xs4[S_DIM];   // per-s, batch-interleaved f32
    __shared__ float  wt[256];      // wt[k] = -2/(pi*(2k+1))^2 (padded: t2 lanes)
    __shared__ float2 csn[A_DIM];   // (cos, sin) per angle
    __shared__ f4     red[256];     // phase-2 partial merge

    const int tid = threadIdx.x;
    const int b   = blockIdx.x;

    if (tid < A_DIM) {
        float th = (float)tid * (F_PI / 180.0f);
        csn[tid] = make_float2(cosf(th), sinf(th));
    }

    // ---------------- Phase 1: ramp filter ----------------
    if (b < A_DIM) {
        const int a = b;
        {   // stage s = tid (0..255) and s = tid+256 (256..362)
            f4 v;
            v.x = x[(0 * S_DIM + tid) * A_DIM + a];
            v.y = x[(1 * S_DIM + tid) * A_DIM + a];
            v.z = x[(2 * S_DIM + tid) * A_DIM + a];
            v.w = x[(3 * S_DIM + tid) * A_DIM + a];
            xs4[tid] = v;
            const int s2 = tid + 256;
            if (s2 < S_DIM) {
                f4 w;
                w.x = x[(0 * S_DIM + s2) * A_DIM + a];
                w.y = x[(1 * S_DIM + s2) * A_DIM + a];
                w.z = x[(2 * S_DIM + s2) * A_DIM + a];
                w.w = x[(3 * S_DIM + s2) * A_DIM + a];
                xs4[s2] = w;
            }
        }
        {
            float d = (float)(2 * tid + 1);
            wt[tid] = -2.0f / (F_PI * F_PI * d * d);
        }
        __syncthreads();

        if (tid < 192) {
            const int t1 = tid;
            const int t2 = tid + 192;                    // valid iff < S_DIM
            f4 acc1 = 0.5f * xs4[t1];                    // d == 0 terms (f32 exact)
            f4 acc2 = 0.5f * xs4[(t2 < S_DIM) ? t2 : 0]; // discarded if invalid

            const int s0 = 1 - (tid & 1);                // opposite parity of t1 (== t2)
            #pragma unroll 4
            for (int s = s0; s < S_DIM; s += 2) {
                f4 v = xs4[s];                           // one b128, shared by 2 outputs
                int d1 = s - t1; d1 = (d1 < 0) ? -d1 : d1;
                int d2 = s - t2; d2 = (d2 < 0) ? -d2 : d2;   // <= 383 -> wt idx <= 191
                acc1 += wt[d1 >> 1] * v;                 // 2x v_pk_fma_f32 each
                acc2 += wt[d2 >> 1] * v;
            }

            HU r1; r1.h = __builtin_convertvector(acc1, h4);
            g_sino[a * S_P + 1 + t1] = r1.u;
            if (t2 < S_DIM) {
                HU r2; r2.h = __builtin_convertvector(acc2, h4);
                g_sino[a * S_P + 1 + t2] = r2.u;
            }
        }
        if (tid == 252) { HU z; z.u.x = 0u; z.u.y = 0u; g_sino[a * S_P + 0]   = z.u; }
        if (tid == 253) { HU z; z.u.x = 0u; z.u.y = 0u; g_sino[a * S_P + 364] = z.u; }
    }

    // ---------------- Grid barrier (capacity + agent-scope atomics) --------
    __syncthreads();                       // block's phase-1 stores issued
    if (tid == 0) {
        __threadfence();                   // release g_sino (agent scope)
        unsigned t = __hip_atomic_fetch_add(&g_bar, 1u, __ATOMIC_ACQ_REL,
                                            __HIP_MEMORY_SCOPE_AGENT);
        unsigned target = (t / GRIDN + 1u) * GRIDN;
        while (__hip_atomic_load(&g_bar, __ATOMIC_ACQUIRE,
                                 __HIP_MEMORY_SCOPE_AGENT) < target) {
            __builtin_amdgcn_s_sleep(2);
        }
        __threadfence();                   // acquire: no stale g_sino lines
    }
    __syncthreads();                       // whole block sees the barrier

    // ---------------- Phase 2: backprojection ----------------
    const int px = tid & 63;
    const int q  = tid >> 6;             // wave index = angle quarter (uniform/wave)
    const int jx = b & 3;
    const int j  = jx * 64 + px;
    const float jj = (float)(j - 128);
    const int a0 = q * 45;

    #pragma unroll 2
    for (int half = 0; half < 2; ++half) {
        const int i = (b >> 2) + half * 128;   // two output rows per block
        const float nii = (float)(128 - i);    // -(i-128), wave-uniform

        f4 acc = (f4)0.0f;
        #pragma unroll 5
        for (int m = 0; m < 45; ++m) {
            const int a = a0 + m;
            const float2 cn = csn[a];          // one ds_read_b64 broadcast
            float pos = fmaf(jj, cn.x, fmaf(nii, cn.y, 181.0f));
            float f   = floorf(pos);
            int   k1  = (int)f + 1;            // in [0, 363]
            float w1  = pos - f;
            float w0  = 1.0f - w1;
            const uint2* __restrict__ row = g_sino + a * S_P;
            HU lo, hi;
            lo.u = row[k1];                    // y[k]   x4 batches (8 B)
            hi.u = row[k1 + 1];                // y[k+1] x4 batches (offset:8)
            acc.x = fmaf((float)lo.h.x, w0, fmaf((float)hi.h.x, w1, acc.x));
            acc.y = fmaf((float)lo.h.y, w0, fmaf((float)hi.h.y, w1, acc.y));
            acc.z = fmaf((float)lo.h.z, w0, fmaf((float)hi.h.z, w1, acc.z));
            acc.w = fmaf((float)lo.h.w, w0, fmaf((float)hi.h.w, w1, acc.w));
        }

        red[tid] = acc;
        __syncthreads();

        if (tid < 64) {
            f4 r = red[tid] + red[tid + 64] + red[tid + 128] + red[tid + 192];
            r *= (F_PI / 360.0f);
            const int jo   = jx * 64 + tid;
            const size_t p = (size_t)i * OUT_W + jo;
            out[p]              = r.x;
            out[p +     65536]  = r.y;
            out[p + 2 * 65536]  = r.z;
            out[p + 3 * 65536]  = r.w;
        }
        __syncthreads();
    }
}

extern "C" void kernel_launch(void* const* d_in, const int* in_sizes, int n_in,
                              void* d_out, int out_size, void* d_ws, size_t ws_size,
                              hipStream_t stream) {
    const float* x = (const float*)d_in[0];
    float* out = (float*)d_out;

    iradon_fused_kernel<<<dim3(GRIDN), 256, 0, stream>>>(x, out);
}

// Round 5
// 120.661 us; speedup vs baseline: 1.2333x; 1.2333x over previous
//
#include <hip/hip_runtime.h>

#define S_DIM 363      // GRID = ceil(sqrt(2)*256)
#define S_P   368      // per-angle row stride in 8-B entries (16-B multiple)
#define A_DIM 180      // N_THETA
#define OUT_W 256
#define GRIDN 512      // fused-kernel grid: 2 blocks/CU x 256 CU = co-resident
#define F_PI 3.14159265358979323846f
#define W_C  (-2.0f / (F_PI * F_PI))   // conv weight scale: w(d) = W_C / d^2

typedef float    f4 __attribute__((ext_vector_type(4)));
typedef _Float16 h4 __attribute__((ext_vector_type(4)));
union HU { uint2 u; h4 h; };

// Filtered sinogram, plain fp16 layout: g_sino[a*S_P + 1 + t] = y_a[t] for all
// 4 batches (8 B, batch-interleaved). Guards g[a][0] = g[a][364] = 0 reproduce
// the reference's clip+zero-weight edge semantics exactly (k1 = floor(pos)+1
// in [0,363]; lo = entry k1 = y[k1-1] or guard, hi = entry k1+1 = y[k1] or
// guard). Fully rewritten every launch before phase 2 reads it.
__device__ uint2 g_sino[A_DIM * S_P];

// Grid barrier state. Monotonic: every launch adds exactly GRIDN, so the
// counter is a multiple of GRIDN at each launch start -- safe across hip-graph
// replays with no host-side reset.
__device__ unsigned g_bar = 0u;

// ---------------------------------------------------------------------------
// Fused kernel, ONE plain dispatch. R4 post-mortem: the 104 us kernel time was
// the barrier's ACQUIRE-per-poll (each agent-scope acquire = vmcnt(0) + L2
// invalidate; 512 spinners x ~2k polls = L2s permanently invalidating).
// Fix: RELAXED fetch_add + RELAXED polls, ONE release fence before arrival and
// ONE acquire fence after exit. Same visibility guarantees (fence-based
// release/acquire), none of the per-poll cache maintenance.
//
// Phase 1 (blocks 0..179, one angle each): ramp filter as direct spatial conv
//   (exact rewrite of the reference FFT path: circular conv, g[0]=0.5,
//   g[d]=-2/(pi*d)^2 odd d, 0 even d; |t-s| <= 362 < 512 so the weight
//   depends only on |t-s|). R5 change: weights computed by v_rcp_f32
//   (w = W_C * rcp(d^2), ~1e-7 rel err, invisible under fp16 storage) instead
//   of LDS table -> hot loop has ONE LDS read (broadcast b128) per iter; at
//   ~1 wave/SIMD the removed LDS round-trips were latency-exposed (R1-K1 ran
//   ~2x its issue model). 256 threads, two outputs each (t, t+256 -- same
//   parity -> shared xs4[s] read).
//
// Phase 2 (all 512 blocks, 2 output rows each: i = b>>2 and i+128, j-chunk
//   b&3): pos = (j-128)*cos - (i-128)*sin + 181; k1 = floor(pos)+1 in
//   [0,363]; two adjacent 8-B loads (second folds to offset:8) give both
//   interp taps x4 batches; f32 accum via v_fma_mix. 4 waves = 4 angle
//   quarters, partials merged through LDS.
// ---------------------------------------------------------------------------
__global__ __launch_bounds__(256, 2) void iradon_fused_kernel(
        const float* __restrict__ x, float* __restrict__ out) {
    __shared__ f4     xs4[S_DIM];   // per-s, batch-interleaved f32
    __shared__ float2 csn[A_DIM];   // (cos, sin) per angle
    __shared__ f4     red[256];     // phase-2 partial merge

    const int tid = threadIdx.x;
    const int b   = blockIdx.x;

    if (tid < A_DIM) {
        float th = (float)tid * (F_PI / 180.0f);
        csn[tid] = make_float2(cosf(th), sinf(th));
    }

    // ---------------- Phase 1: ramp filter ----------------
    if (b < A_DIM) {
        const int a = b;
        {   // stage s = tid (0..255) and s = tid+256 (256..362)
            f4 v;
            v.x = x[(0 * S_DIM + tid) * A_DIM + a];
            v.y = x[(1 * S_DIM + tid) * A_DIM + a];
            v.z = x[(2 * S_DIM + tid) * A_DIM + a];
            v.w = x[(3 * S_DIM + tid) * A_DIM + a];
            xs4[tid] = v;
            const int s2 = tid + 256;
            if (s2 < S_DIM) {
                f4 w;
                w.x = x[(0 * S_DIM + s2) * A_DIM + a];
                w.y = x[(1 * S_DIM + s2) * A_DIM + a];
                w.z = x[(2 * S_DIM + s2) * A_DIM + a];
                w.w = x[(3 * S_DIM + s2) * A_DIM + a];
                xs4[s2] = w;
            }
        }
        __syncthreads();

        {
            const int t1 = tid;               // 0..255, always valid
            const int t2 = tid + 256;         // valid iff < S_DIM (tid <= 106)
            f4 acc1 = 0.5f * xs4[t1];         // d == 0 terms (f32 exact)
            f4 acc2 = 0.5f * xs4[(t2 < S_DIM) ? t2 : 0];  // discarded if invalid

            const float tf1 = (float)t1;
            const float tf2 = (float)t2;
            const int   s0  = 1 - (tid & 1);  // opposite parity of t1 (== t2)
            float sf = (float)s0;
            #pragma unroll 4
            for (int s = s0; s < S_DIM; s += 2, sf += 2.0f) {
                f4 v = xs4[s];                // ONE b128 broadcast, shared by 2 outputs
                float d1 = sf - tf1;          // |d| odd >= 1; never 0 (parity)
                float d2 = sf - tf2;          // t2 > 362 lanes: d2 != 0, garbage ok
                float w1 = W_C * __builtin_amdgcn_rcpf(d1 * d1);
                float w2 = W_C * __builtin_amdgcn_rcpf(d2 * d2);
                acc1 += w1 * v;               // 2x v_pk_fma_f32 each
                acc2 += w2 * v;
            }

            HU r1; r1.h = __builtin_convertvector(acc1, h4);
            g_sino[a * S_P + 1 + t1] = r1.u;
            if (t2 < S_DIM) {
                HU r2; r2.h = __builtin_convertvector(acc2, h4);
                g_sino[a * S_P + 1 + t2] = r2.u;
            }
        }
        if (tid == 252) { HU z; z.u.x = 0u; z.u.y = 0u; g_sino[a * S_P + 0]   = z.u; }
        if (tid == 253) { HU z; z.u.x = 0u; z.u.y = 0u; g_sino[a * S_P + 364] = z.u; }
    }

    // ------- Grid barrier: capacity + relaxed atomics, fences at edges -----
    __syncthreads();                       // block's phase-1 stores issued
    if (tid == 0) {
        __threadfence();                   // release g_sino (one L2 writeback)
        unsigned t = __hip_atomic_fetch_add(&g_bar, 1u, __ATOMIC_RELAXED,
                                            __HIP_MEMORY_SCOPE_AGENT);
        unsigned target = (t / GRIDN + 1u) * GRIDN;
        while (__hip_atomic_load(&g_bar, __ATOMIC_RELAXED,
                                 __HIP_MEMORY_SCOPE_AGENT) < target) {
            __builtin_amdgcn_s_sleep(8);   // ~512 cy between polls
        }
        __threadfence();                   // acquire: drop stale g_sino lines
    }
    __syncthreads();                       // whole block sees the barrier

    // ---------------- Phase 2: backprojection ----------------
    const int px = tid & 63;
    const int q  = tid >> 6;             // wave index = angle quarter (uniform/wave)
    const int jx = b & 3;
    const int j  = jx * 64 + px;
    const float jj = (float)(j - 128);
    const int a0 = q * 45;

    #pragma unroll 2
    for (int half = 0; half < 2; ++half) {
        const int i = (b >> 2) + half * 128;   // two output rows per block
        const float nii = (float)(128 - i);    // -(i-128), wave-uniform

        f4 acc = (f4)0.0f;
        #pragma unroll 5
        for (int m = 0; m < 45; ++m) {
            const int a = a0 + m;
            const float2 cn = csn[a];          // one ds_read_b64 broadcast
            float pos = fmaf(jj, cn.x, fmaf(nii, cn.y, 181.0f));
            float f   = floorf(pos);
            int   k1  = (int)f + 1;            // in [0, 363]
            float w1  = pos - f;
            float w0  = 1.0f - w1;
            const uint2* __restrict__ row = g_sino + a * S_P;
            HU lo, hi;
            lo.u = row[k1];                    // y[k]   x4 batches (8 B)
            hi.u = row[k1 + 1];                // y[k+1] x4 batches (offset:8)
            acc.x = fmaf((float)lo.h.x, w0, fmaf((float)hi.h.x, w1, acc.x));
            acc.y = fmaf((float)lo.h.y, w0, fmaf((float)hi.h.y, w1, acc.y));
            acc.z = fmaf((float)lo.h.z, w0, fmaf((float)hi.h.z, w1, acc.z));
            acc.w = fmaf((float)lo.h.w, w0, fmaf((float)hi.h.w, w1, acc.w));
        }

        red[tid] = acc;
        __syncthreads();

        if (tid < 64) {
            f4 r = red[tid] + red[tid + 64] + red[tid + 128] + red[tid + 192];
            r *= (F_PI / 360.0f);
            const int jo   = jx * 64 + tid;
            const size_t p = (size_t)i * OUT_W + jo;
            out[p]              = r.x;
            out[p +     65536]  = r.y;
            out[p + 2 * 65536]  = r.z;
            out[p + 3 * 65536]  = r.w;
        }
        __syncthreads();
    }
}

extern "C" void kernel_launch(void* const* d_in, const int* in_sizes, int n_in,
                              void* d_out, int out_size, void* d_ws, size_t ws_size,
                              hipStream_t stream) {
    const float* x = (const float*)d_in[0];
    float* out = (float*)d_out;

    iradon_fused_kernel<<<dim3(GRIDN), 256, 0, stream>>>(x, out);
}

// Round 6
// 71.713 us; speedup vs baseline: 2.0752x; 1.6825x over previous
//
#include <hip/hip_runtime.h>

#define S_DIM 363      // GRID = ceil(sqrt(2)*256)
#define S_P   368      // per-angle row stride in 8-B entries (16-B multiple)
#define A_DIM 180      // N_THETA
#define OUT_W 256
#define F_PI 3.14159265358979323846f
#define W_C  (-2.0f / (F_PI * F_PI))   // conv weight scale: w(d) = W_C / d^2

typedef float    f4 __attribute__((ext_vector_type(4)));
typedef _Float16 h4 __attribute__((ext_vector_type(4)));
union HU { uint2 u; h4 h; };

// Filtered sinogram, plain fp16 layout: g_sino[a*S_P + 1 + t] = y_a[t] for all
// 4 batches (8 B, batch-interleaved). Guards g[a][0] = g[a][364] = 0 reproduce
// the reference's clip+zero-weight edge semantics exactly (k1 = floor(pos)+1
// in [0,363]; lo = entry k1 = y[k1-1] or guard, hi = entry k1+1 = y[k1] or
// guard). Fully rewritten every launch before kernel 2 reads it; the kernel
// boundary is the grid barrier (R4/R5 measured software grid barriers at
// ~68 us on this 8-XCD chip vs ~3 us for the dispatch boundary -- fusion is
// a dead end, reverted).
__device__ uint2  g_sino[A_DIM * S_P];
// (cos, sin) per angle, computed ONCE by kernel 1 (one thread per block).
// R1-K2 ran 180 cosf/sinf in EVERY of 1024 blocks (~0.5-1 us ocml prologue
// per block on the critical path); kernel 2 now loads this table coalesced.
__device__ float2 g_csn[A_DIM];

// ---------------------------------------------------------------------------
// Kernel 1: ramp filter as direct spatial convolution (exact rewrite of the
// reference FFT path: circular conv, g[0]=0.5, g[d]=-2/(pi*d)^2 for odd d,
// 0 for even d; |t-s| <= 362 < 512 so weight depends only on |t-s|).
// One block per angle, 256 threads, TWO outputs per thread (t, t+256 -- same
// parity -> shared xs4[s] read). Weights via v_rcp_f32 (w = W_C*rcp(d*d),
// ~1e-7 rel err, invisible under fp16 storage; absmax bit-identical, proven
// R5): hot loop has ONE uniform-address b128 LDS broadcast per iter -- the
// two per-lane b32 weight gathers of the R1 version are gone, their work
// moved to the idle transcendental pipe (VALUBusy was ~12%).
// ---------------------------------------------------------------------------
__global__ __launch_bounds__(256) void iradon_filter_kernel(
        const float* __restrict__ x) {
    __shared__ f4 xs4[S_DIM];      // per-s, batch-interleaved f32

    const int a   = blockIdx.x;    // 0..179
    const int tid = threadIdx.x;   // 0..255

    {   // stage s = tid (0..255) and s = tid+256 (256..362)
        f4 v;
        v.x = x[(0 * S_DIM + tid) * A_DIM + a];
        v.y = x[(1 * S_DIM + tid) * A_DIM + a];
        v.z = x[(2 * S_DIM + tid) * A_DIM + a];
        v.w = x[(3 * S_DIM + tid) * A_DIM + a];
        xs4[tid] = v;
        const int s2 = tid + 256;
        if (s2 < S_DIM) {
            f4 w;
            w.x = x[(0 * S_DIM + s2) * A_DIM + a];
            w.y = x[(1 * S_DIM + s2) * A_DIM + a];
            w.z = x[(2 * S_DIM + s2) * A_DIM + a];
            w.w = x[(3 * S_DIM + s2) * A_DIM + a];
            xs4[s2] = w;
        }
    }
    if (tid == 254) {              // this block's angle -> trig table (once)
        float th = (float)a * (F_PI / 180.0f);
        g_csn[a] = make_float2(cosf(th), sinf(th));
    }
    __syncthreads();

    {
        const int t1 = tid;               // 0..255, always valid
        const int t2 = tid + 256;         // valid iff < S_DIM (tid <= 106)
        f4 acc1 = 0.5f * xs4[t1];         // d == 0 terms (f32 exact)
        f4 acc2 = 0.5f * xs4[(t2 < S_DIM) ? t2 : 0];  // discarded if invalid

        const float tf1 = (float)t1;
        const float tf2 = (float)t2;
        const int   s0  = 1 - (tid & 1);  // opposite parity of t1 (== t2)
        float sf = (float)s0;
        #pragma unroll 4
        for (int s = s0; s < S_DIM; s += 2, sf += 2.0f) {
            f4 v = xs4[s];                // ONE b128 broadcast, shared by 2 outputs
            float d1 = sf - tf1;          // |d| odd >= 1; never 0 (parity)
            float d2 = sf - tf2;          // t2 > 362 lanes: d2 != 0, garbage ok
            float w1 = W_C * __builtin_amdgcn_rcpf(d1 * d1);
            float w2 = W_C * __builtin_amdgcn_rcpf(d2 * d2);
            acc1 += w1 * v;               // 2x v_pk_fma_f32 each
            acc2 += w2 * v;
        }

        HU r1; r1.h = __builtin_convertvector(acc1, h4);
        g_sino[a * S_P + 1 + t1] = r1.u;
        if (t2 < S_DIM) {
            HU r2; r2.h = __builtin_convertvector(acc2, h4);
            g_sino[a * S_P + 1 + t2] = r2.u;
        }
    }
    if (tid == 252) { HU z; z.u.x = 0u; z.u.y = 0u; g_sino[a * S_P + 0]   = z.u; }
    if (tid == 253) { HU z; z.u.x = 0u; z.u.y = 0u; g_sino[a * S_P + 364] = z.u; }
}

// ---------------------------------------------------------------------------
// Kernel 2: backprojection. pos = (j-128)*cos - (i-128)*sin + 181.
// f = floor(pos), k1 = (int)f + 1 in [0,363]: lo = g[a][k1], hi = g[a][k1+1]
// -- two adjacent 8-B loads, second folds to offset:8; f32 accum via
// v_fma_mix. Trig comes from g_csn (two coalesced wave-loads into LDS)
// instead of per-block cosf/sinf. Block = 256 thr = 64(j) x 4 angle-quarters,
// one output row per block; partials merged through LDS. Grid = 4 x 256
// (1024 blocks, 4/CU, 16 waves/CU).
// ---------------------------------------------------------------------------
__global__ __launch_bounds__(256) void iradon_backproject_kernel(
        float* __restrict__ out) {
    __shared__ float2 csn[A_DIM];
    __shared__ f4 red[256];

    const int tid = threadIdx.x;
    if (tid < A_DIM) csn[tid] = g_csn[tid];   // coalesced 8B loads, L2-hit
    __syncthreads();

    const int px = tid & 63;
    const int q  = tid >> 6;           // wave index = angle quarter (uniform/wave)
    const int j  = blockIdx.x * 64 + px;
    const int i  = blockIdx.y;

    const float jj  = (float)(j - 128);
    const float nii = (float)(128 - i);    // -(i-128), wave-uniform

    f4 acc = (f4)0.0f;
    const int a0 = q * 45;
    #pragma unroll 5
    for (int m = 0; m < 45; ++m) {
        const int a = a0 + m;
        const float2 cn = csn[a];          // one ds_read_b64 broadcast
        float pos = fmaf(jj, cn.x, fmaf(nii, cn.y, 181.0f));
        float f   = floorf(pos);
        int   k1  = (int)f + 1;            // in [0, 363]
        float w1  = pos - f;
        float w0  = 1.0f - w1;
        const uint2* __restrict__ row = g_sino + a * S_P;
        HU lo, hi;
        lo.u = row[k1];                    // y[k]   x4 batches (8 B)
        hi.u = row[k1 + 1];                // y[k+1] x4 batches (offset:8)
        acc.x = fmaf((float)lo.h.x, w0, fmaf((float)hi.h.x, w1, acc.x));
        acc.y = fmaf((float)lo.h.y, w0, fmaf((float)hi.h.y, w1, acc.y));
        acc.z = fmaf((float)lo.h.z, w0, fmaf((float)hi.h.z, w1, acc.z));
        acc.w = fmaf((float)lo.h.w, w0, fmaf((float)hi.h.w, w1, acc.w));
    }

    red[tid] = acc;
    __syncthreads();

    if (tid < 64) {
        f4 r = red[tid] + red[tid + 64] + red[tid + 128] + red[tid + 192];
        r *= (F_PI / 360.0f);
        const int jo   = blockIdx.x * 64 + tid;
        const size_t p = (size_t)blockIdx.y * OUT_W + jo;
        out[p]              = r.x;
        out[p +     65536]  = r.y;
        out[p + 2 * 65536]  = r.z;
        out[p + 3 * 65536]  = r.w;
    }
}

extern "C" void kernel_launch(void* const* d_in, const int* in_sizes, int n_in,
                              void* d_out, int out_size, void* d_ws, size_t ws_size,
                              hipStream_t stream) {
    const float* x = (const float*)d_in[0];
    float* out = (float*)d_out;

    iradon_filter_kernel<<<dim3(A_DIM), 256, 0, stream>>>(x);
    iradon_backproject_kernel<<<dim3(4, OUT_W), 256, 0, stream>>>(out);
}

// Round 7
// 68.706 us; speedup vs baseline: 2.1660x; 1.0438x over previous
//
#include <hip/hip_runtime.h>

#define S_DIM 363      // GRID = ceil(sqrt(2)*256)
#define S_P   368      // per-angle row stride in 8-B entries (16-B multiple)
#define A_DIM 180      // N_THETA
#define OUT_W 256
#define F_PI 3.14159265358979323846f
#define W_C  (-2.0f / (F_PI * F_PI))   // conv weight scale: w(d) = W_C / d^2

typedef float    f4 __attribute__((ext_vector_type(4)));
typedef _Float16 h4 __attribute__((ext_vector_type(4)));
union HU { uint2 u; h4 h; };

// Filtered sinogram, plain fp16 layout: g_sino[a*S_P + 1 + t] = y_a[t] for all
// 4 batches (8 B, batch-interleaved). Guards g[a][0] = g[a][364] = 0 reproduce
// the reference's clip+zero-weight edge semantics exactly (k1 = floor(pos)+1
// in [0,363]; lo = entry k1 = y[k1-1] or guard, hi = entry k1+1 = y[k1] or
// guard). Fully rewritten every launch before kernel 2 reads it; the kernel
// boundary is the grid barrier (R4/R5: software grid barriers cost ~30-70 us
// on this 8-XCD chip vs ~3 us for the dispatch boundary -- fusion dead end).
__device__ uint2  g_sino[A_DIM * S_P];
// (cos, sin) per angle, computed ONCE by kernel 1 (one thread per block).
__device__ float2 g_csn[A_DIM];

// ---------------------------------------------------------------------------
// Kernel 1: ramp filter as direct spatial convolution (exact rewrite of the
// reference FFT path: circular conv, g[0]=0.5, g[d]=-2/(pi*d)^2 for odd d,
// 0 for even d; |t-s| <= 362 < 512 so weight depends only on |t-s|).
//
// R7 restructure -- the R0..R6 record shows issue-count cuts move <=1.2 us
// while the kernel runs 1 wave/SIMD (critical path = one wave's serial loop
// at low small-kernel clocks). So: SPLIT-SUM. 768 threads (12 waves,
// 3/SIMD). Output t's ~181 odd-distance taps are partitioned by
// (s-t) mod 4 ∈ {1,3} into two uniform ~91-tap step-4 progressions:
// thread u < 363 accumulates the (t+1 mod 4) half, thread u+363 the
// (t+3 mod 4) half; halves merge through LDS with the 0.5*x[t] term.
// Uniform trip count (no divergence); 4 distinct LDS addrs/wave,
// conflict-free. Weights via v_rcp_f32 (w = W_C*rcp(d*d), ~1e-7 rel err,
// invisible under fp16 storage -- proven R5/R6). Staging spread 768 wide
// (2 scalar loads/thread vs 8).
// ---------------------------------------------------------------------------
__global__ __launch_bounds__(768) void iradon_filter_kernel(
        const float* __restrict__ x) {
    __shared__ f4 xs4[S_DIM];      // per-s, batch-interleaved f32
    __shared__ f4 red[726];        // half-sums: [0,363) = h0, [363,726) = h1

    const int a   = blockIdx.x;    // 0..179
    const int tid = threadIdx.x;   // 0..767

    // ---- stage: 1452 scalars (4 batches x 363 s), 2 per thread, scattered
    {
        float* lds = (float*)xs4;  // element (s, b) at index s*4 + b
        int n = tid;               // n = b*363 + s
        #pragma unroll 2
        for (int r = 0; r < 2; ++r, n += 768) {
            if (n < 4 * S_DIM) {
                int b = (n >= 3 * S_DIM) ? 3 : (n >= 2 * S_DIM) ? 2
                      : (n >= S_DIM) ? 1 : 0;
                int s = n - b * S_DIM;
                lds[s * 4 + b] = x[n * A_DIM + a];   // x[(b*363+s)*180 + a]
            }
        }
    }
    if (tid == 728) {              // this block's angle -> trig table (once)
        float th = (float)a * (F_PI / 180.0f);
        g_csn[a] = make_float2(cosf(th), sinf(th));
    }
    __syncthreads();

    // ---- split-sum conv: thread u handles output t = u % 363, half u / 363
    if (tid < 726) {
        const int t  = (tid >= S_DIM) ? tid - S_DIM : tid;
        const int p0 = (tid >= S_DIM) ? ((t + 3) & 3) : ((t + 1) & 3);
        f4 acc = (f4)0.0f;
        float df = (float)(p0 - t);          // d = s - t, steps by 4
        #pragma unroll 4
        for (int s = p0; s < S_DIM; s += 4, df += 4.0f) {
            f4 v = xs4[s];                   // 4 phase-addrs/wave, conflict-free
            float w = W_C * __builtin_amdgcn_rcpf(df * df);
            acc += w * v;                    // 2x v_pk_fma_f32
        }
        red[tid] = acc;
    }
    __syncthreads();

    // ---- merge halves + d==0 term, convert to fp16, store
    if (tid < S_DIM) {
        f4 tot = 0.5f * xs4[tid] + red[tid] + red[tid + S_DIM];
        HU r; r.h = __builtin_convertvector(tot, h4);
        g_sino[a * S_P + 1 + tid] = r.u;
    }
    if (tid == 726) { HU z; z.u.x = 0u; z.u.y = 0u; g_sino[a * S_P + 0]   = z.u; }
    if (tid == 727) { HU z; z.u.x = 0u; z.u.y = 0u; g_sino[a * S_P + 364] = z.u; }
}

// ---------------------------------------------------------------------------
// Kernel 2: backprojection (unchanged from R6 -- proven stable).
// pos = (j-128)*cos - (i-128)*sin + 181; f = floor(pos), k1 = (int)f + 1 in
// [0,363]: lo = g[a][k1], hi = g[a][k1+1] -- two adjacent 8-B loads, second
// folds to offset:8; f32 accum via v_fma_mix. Trig from g_csn (coalesced,
// L2-hit). Block = 256 thr = 64(j) x 4 angle-quarters, one output row per
// block; partials merged through LDS. Grid = 4 x 256 (1024 blocks, 4/CU).
// ---------------------------------------------------------------------------
__global__ __launch_bounds__(256) void iradon_backproject_kernel(
        float* __restrict__ out) {
    __shared__ float2 csn[A_DIM];
    __shared__ f4 red[256];

    const int tid = threadIdx.x;
    if (tid < A_DIM) csn[tid] = g_csn[tid];   // coalesced 8B loads, L2-hit
    __syncthreads();

    const int px = tid & 63;
    const int q  = tid >> 6;           // wave index = angle quarter (uniform/wave)
    const int j  = blockIdx.x * 64 + px;
    const int i  = blockIdx.y;

    const float jj  = (float)(j - 128);
    const float nii = (float)(128 - i);    // -(i-128), wave-uniform

    f4 acc = (f4)0.0f;
    const int a0 = q * 45;
    #pragma unroll 5
    for (int m = 0; m < 45; ++m) {
        const int a = a0 + m;
        const float2 cn = csn[a];          // one ds_read_b64 broadcast
        float pos = fmaf(jj, cn.x, fmaf(nii, cn.y, 181.0f));
        float f   = floorf(pos);
        int   k1  = (int)f + 1;            // in [0, 363]
        float w1  = pos - f;
        float w0  = 1.0f - w1;
        const uint2* __restrict__ row = g_sino + a * S_P;
        HU lo, hi;
        lo.u = row[k1];                    // y[k]   x4 batches (8 B)
        hi.u = row[k1 + 1];                // y[k+1] x4 batches (offset:8)
        acc.x = fmaf((float)lo.h.x, w0, fmaf((float)hi.h.x, w1, acc.x));
        acc.y = fmaf((float)lo.h.y, w0, fmaf((float)hi.h.y, w1, acc.y));
        acc.z = fmaf((float)lo.h.z, w0, fmaf((float)hi.h.z, w1, acc.z));
        acc.w = fmaf((float)lo.h.w, w0, fmaf((float)hi.h.w, w1, acc.w));
    }

    red[tid] = acc;
    __syncthreads();

    if (tid < 64) {
        f4 r = red[tid] + red[tid + 64] + red[tid + 128] + red[tid + 192];
        r *= (F_PI / 360.0f);
        const int jo   = blockIdx.x * 64 + tid;
        const size_t p = (size_t)blockIdx.y * OUT_W + jo;
        out[p]              = r.x;
        out[p +     65536]  = r.y;
        out[p + 2 * 65536]  = r.z;
        out[p + 3 * 65536]  = r.w;
    }
}

extern "C" void kernel_launch(void* const* d_in, const int* in_sizes, int n_in,
                              void* d_out, int out_size, void* d_ws, size_t ws_size,
                              hipStream_t stream) {
    const float* x = (const float*)d_in[0];
    float* out = (float*)d_out;

    iradon_filter_kernel<<<dim3(A_DIM), 768, 0, stream>>>(x);
    iradon_backproject_kernel<<<dim3(4, OUT_W), 256, 0, stream>>>(out);
}